// Round 5
// baseline (67.640 us; speedup 1.0000x reference)
//
#include <hip/hip_runtime.h>

#define N_NODES 40000
#define C_DIM   128
#define K_NBR   16

static constexpr float BETA_F  = 0.11778303565638346f;  // log(1.125)
static constexpr float C1_F    = 0.7939952679092549f;   // (1-ALPHA)*(1-BETA)
static constexpr float C2_F    = 0.08822169643436166f;  // ALPHA*(1-BETA)
static constexpr float INV_DEG = 1.0f / 17.0f;

typedef __attribute__((ext_vector_type(8))) short bf16x8;
typedef __attribute__((ext_vector_type(4))) float f32x4;

__device__ __forceinline__ unsigned pack_bf16x2(float a, float b) {
    unsigned ua = __float_as_uint(a), ub = __float_as_uint(b);
    ua += 0x7fffu + ((ua >> 16) & 1u);     // RNE
    ub += 0x7fffu + ((ub >> 16) & 1u);
    return (ua >> 16) | (ub & 0xffff0000u);
}
__device__ __forceinline__ float bflo(unsigned u) { return __uint_as_float(u << 16); }
__device__ __forceinline__ float bfhi(unsigned u) { return __uint_as_float(u & 0xffff0000u); }

// ---------------------------------------------------------------------------
// Kernel 1 (prep):
//   blocks 0..624 : transpose+cast 64 nodes x ALL 128 channels of
//                   x [128][40000] f32 -> xTb [N][64] u32(bf16x2).
//                   Each wave writes 16 COMPLETE 256-B xTb rows (4 KB
//                   contiguous) -> no partial-line / cross-block sharing.
//   block  625    : build folded weight fragments W' (bf16, frag-major).
// W'[c][o] = c<128 ? (BETA*W1[o][c] + (c==o)*C1) * INV_DEG
//                  : BETA*W2[o][c-128] + (c-128==o)*C2
// ---------------------------------------------------------------------------
__global__ __launch_bounds__(256) void prep_kernel(
        const float* __restrict__ x,
        const float* __restrict__ W1,
        const float* __restrict__ W2,
        unsigned* __restrict__ xTb,
        unsigned short* __restrict__ WB) {
    __shared__ unsigned lds[64 * 65];   // [n][c2], stride 65 u32 (16640 B)

    const int b = blockIdx.x;
    if (b == 625) {
        const int tid = threadIdx.x;
#pragma unroll 4
        for (int it = 0; it < 128; ++it) {
            int i = it * 256 + tid;
            int frag = i >> 9, within = i & 511;
            int lane = within >> 3, j = within & 7;
            int otile = frag >> 3, kblk = frag & 7;
            int o = otile * 16 + (lane & 15);
            int c = kblk * 32 + ((lane >> 4) << 3) + j;
            float v;
            if (c < 128) {
                v = (BETA_F * W1[o * 128 + c] + (c == o ? C1_F : 0.0f)) * INV_DEG;
            } else {
                int c2 = c - 128;
                v = BETA_F * W2[o * 128 + c2] + (c2 == o ? C2_F : 0.0f);
            }
            unsigned u = __float_as_uint(v);
            u += 0x7fffu + ((u >> 16) & 1u);
            WB[i] = (unsigned short)(u >> 16);
        }
        return;
    }

    const int nb  = b * 64;
    const int tid = threadIdx.x;

    // ---- load + pack: task t = tid + 256*i ; c2 = t>>4 (0..63), g = t&15 ----
#pragma unroll
    for (int i = 0; i < 4; ++i) {
        const int t  = tid + 256 * i;
        const int c2 = t >> 4;
        const int g  = t & 15;
        const float4 va = *(const float4*)&x[(size_t)(2 * c2)     * N_NODES + nb + g * 4];
        const float4 vb = *(const float4*)&x[(size_t)(2 * c2 + 1) * N_NODES + nb + g * 4];
        lds[(g * 4 + 0) * 65 + c2] = pack_bf16x2(va.x, vb.x);
        lds[(g * 4 + 1) * 65 + c2] = pack_bf16x2(va.y, vb.y);
        lds[(g * 4 + 2) * 65 + c2] = pack_bf16x2(va.z, vb.z);
        lds[(g * 4 + 3) * 65 + c2] = pack_bf16x2(va.w, vb.w);
    }
    __syncthreads();

    // ---- write: thread (n = tid>>2, q = tid&3) -> 64 B contiguous;
    //      wave -> 16 complete rows = 4 KB contiguous ----
    const int n = tid >> 2, q = tid & 3;
    const unsigned* src = &lds[n * 65 + q * 16];
    unsigned* dst = &xTb[(size_t)(nb + n) * 64 + q * 16];
#pragma unroll
    for (int jj = 0; jj < 4; ++jj) {
        uint4 v = make_uint4(src[4 * jj + 0], src[4 * jj + 1],
                             src[4 * jj + 2], src[4 * jj + 3]);
        *(uint4*)&dst[4 * jj] = v;
    }
}

// ---------------------------------------------------------------------------
// Kernel 2: fused gather-sum + MFMA GEMM (folded W') + relu/bias epilogue.
// Block = 256 threads (4 waves), 32 nodes/block, grid = 1250.
// ---------------------------------------------------------------------------
__global__ __launch_bounds__(256) void fused3_kernel(
        const unsigned* __restrict__ xTb,     // [N][64] u32 = bf16x2
        const float*    __restrict__ x0,      // [N][128] f32
        const int*      __restrict__ e0,      // [N][16]
        const bf16x8*   __restrict__ WB,      // 64 frags x 64 lanes x 16B
        const float*    __restrict__ bias,    // [128]
        float*          __restrict__ out) {   // [128][N]
    __shared__ unsigned y[32][132];           // [node][sum(64) | x0(64) | pad 4]
    __shared__ int eis[512];

    const int nb   = blockIdx.x * 32;
    const int tid  = threadIdx.x;
    const int lane = tid & 63;
    const int wid  = tid >> 6;

    eis[tid]       = e0[(size_t)nb * K_NBR + tid];
    eis[256 + tid] = e0[(size_t)nb * K_NBR + 256 + tid];
    __syncthreads();

    // ---- Phase 1: paired gather (half-wave per node, 4 channels/lane) ----
    const int h  = lane >> 5;
    const int l5 = lane & 31;
#pragma unroll 2
    for (int p4 = 0; p4 < 4; ++p4) {
        const int local = wid * 8 + p4 * 2 + h;
        const int n = nb + local;
        const uint2 sv = *(const uint2*)&xTb[(size_t)n * 64 + 2 * l5];
        float a0 = bflo(sv.x), a1 = bfhi(sv.x);
        float a2 = bflo(sv.y), a3 = bfhi(sv.y);
        const int* ep = &eis[local * K_NBR];
#pragma unroll
        for (int k = 0; k < K_NBR; ++k) {
            const int j = ep[k];
            const uint2 v = *(const uint2*)&xTb[(size_t)j * 64 + 2 * l5];
            a0 += bflo(v.x); a1 += bfhi(v.x);
            a2 += bflo(v.y); a3 += bfhi(v.y);
        }
        *(uint2*)&y[local][2 * l5] =
            make_uint2(pack_bf16x2(a0, a1), pack_bf16x2(a2, a3));
        const float4 xv = *(const float4*)&x0[(size_t)n * C_DIM + 4 * l5];
        *(uint2*)&y[local][64 + 2 * l5] =
            make_uint2(pack_bf16x2(xv.x, xv.y), pack_bf16x2(xv.z, xv.w));
    }
    __syncthreads();

    // ---- Phase 2: MFMA GEMM (K=256) ----
    const int nh = wid & 1;
    const int oh = wid >> 1;
    const int arow = nh * 16 + (lane & 15);
    const int acol = (lane >> 4) * 4;

    bf16x8 afrag[8];
#pragma unroll
    for (int kb = 0; kb < 8; ++kb)
        afrag[kb] = *(const bf16x8*)&y[arow][kb * 16 + acol];

    f32x4 acc[4];
#pragma unroll
    for (int t = 0; t < 4; ++t) {
        f32x4 a = {0.f, 0.f, 0.f, 0.f};
#pragma unroll
        for (int kb = 0; kb < 8; ++kb) {
            bf16x8 bv = WB[((oh * 4 + t) * 8 + kb) * 64 + lane];
            a = __builtin_amdgcn_mfma_f32_16x16x32_bf16(afrag[kb], bv, a, 0, 0, 0);
        }
        acc[t] = a;
    }

    // ---- Phase 3: relu(acc + bias), store [C][N] ----
    const int rbase = nh * 16 + (lane >> 4) * 4;
#pragma unroll
    for (int t = 0; t < 4; ++t) {
        const int o = oh * 64 + t * 16 + (lane & 15);
        const float bo = bias[o];
        float4 res;
        res.x = fmaxf(acc[t][0] + bo, 0.0f);
        res.y = fmaxf(acc[t][1] + bo, 0.0f);
        res.z = fmaxf(acc[t][2] + bo, 0.0f);
        res.w = fmaxf(acc[t][3] + bo, 0.0f);
        *(float4*)&out[(size_t)o * N_NODES + nb + rbase] = res;
    }
}

// ---------------------------------------------------------------------------
extern "C" void kernel_launch(void* const* d_in, const int* in_sizes, int n_in,
                              void* d_out, int out_size, void* d_ws, size_t ws_size,
                              hipStream_t stream) {
    const float* x    = (const float*)d_in[0];   // [1,128,40000,1]
    const float* x0   = (const float*)d_in[1];   // [1,40000,128]
    const int*   ei   = (const int*)  d_in[2];   // [2,1,40000,16]; row 0
    const float* W1   = (const float*)d_in[3];   // [128,128]
    const float* W2   = (const float*)d_in[4];   // [128,128]
    const float* bias = (const float*)d_in[5];   // [128]
    float* out = (float*)d_out;                  // [1,128,40000,1]

    // ws: [0, 64KB) WB' bf16 frags ; [64KB, 64KB+10.24MB) xTb
    unsigned short* WB  = (unsigned short*)d_ws;
    unsigned*       xTb = (unsigned*)((char*)d_ws + 65536);

    hipLaunchKernelGGL(prep_kernel, dim3(626), dim3(256), 0, stream,
                       x, W1, W2, xTb, WB);
    hipLaunchKernelGGL(fused3_kernel, dim3(1250), dim3(256), 0, stream,
                       xTb, x0, ei, (const bf16x8*)WB, bias, out);
}

// Round 6
// 42.935 us; speedup vs baseline: 1.5754x; 1.5754x over previous
//
#include <hip/hip_runtime.h>

#define N_NODES 40000
#define C_DIM   128
#define K_NBR   16

static constexpr float BETA_F  = 0.11778303565638346f;  // log(1.125)
static constexpr float C1_F    = 0.7939952679092549f;   // (1-ALPHA)*(1-BETA)
static constexpr float C2_F    = 0.08822169643436166f;  // ALPHA*(1-BETA)
static constexpr float INV_DEG = 1.0f / 17.0f;

typedef __attribute__((ext_vector_type(8))) short bf16x8;
typedef __attribute__((ext_vector_type(4))) float f32x4;

__device__ __forceinline__ unsigned pack_bf16x2(float a, float b) {
    unsigned ua = __float_as_uint(a), ub = __float_as_uint(b);
    ua += 0x7fffu + ((ua >> 16) & 1u);     // RNE
    ub += 0x7fffu + ((ub >> 16) & 1u);
    return (ua >> 16) | (ub & 0xffff0000u);
}
__device__ __forceinline__ float bflo(unsigned u) { return __uint_as_float(u << 16); }
__device__ __forceinline__ float bfhi(unsigned u) { return __uint_as_float(u & 0xffff0000u); }

// ---------------------------------------------------------------------------
// Kernel 1 (prep):
//   blocks 0..624   : transpose+cast 64 nodes x ALL 128 channels of
//                     x [128][40000] f32 -> xTb [N][64] u32(bf16x2).
//                     Wave writes 16 complete 256-B xTb rows (4 KB contig).
//   blocks 625..752 : build folded weight fragments W' (bf16, frag-major) —
//                     FULLY PARALLEL: 256 elements per block, 1 load + 1
//                     store per thread, no loop (R5's single-block serial
//                     W-build was a 45 us tail at ~0.05% occupancy).
// W'[c][o] = c<128 ? (BETA*W1[o][c] + (c==o)*C1) * INV_DEG
//                  : BETA*W2[o][c-128] + (c-128==o)*C2
// Fragment map = A-frag slot map: frag f = otile*8+kblk;
// o = otile*16+(lane&15), c = kblk*32+(lane>>4)*8+j.
// ---------------------------------------------------------------------------
__global__ __launch_bounds__(256) void prep_kernel(
        const float* __restrict__ x,
        const float* __restrict__ W1,
        const float* __restrict__ W2,
        unsigned* __restrict__ xTb,
        unsigned short* __restrict__ WB) {
    __shared__ unsigned lds[64 * 65];   // [n][c2], stride 65 u32 (16640 B)

    const int b = blockIdx.x;
    if (b >= 625) {
        const int i = (b - 625) * 256 + threadIdx.x;   // 0 .. 32767
        const int frag = i >> 9, within = i & 511;
        const int lane = within >> 3, j = within & 7;
        const int otile = frag >> 3, kblk = frag & 7;
        const int o = otile * 16 + (lane & 15);
        const int c = kblk * 32 + ((lane >> 4) << 3) + j;
        float v;
        if (c < 128) {
            v = (BETA_F * W1[o * 128 + c] + (c == o ? C1_F : 0.0f)) * INV_DEG;
        } else {
            const int c2 = c - 128;
            v = BETA_F * W2[o * 128 + c2] + (c2 == o ? C2_F : 0.0f);
        }
        unsigned u = __float_as_uint(v);
        u += 0x7fffu + ((u >> 16) & 1u);
        WB[i] = (unsigned short)(u >> 16);
        return;
    }

    const int nb  = b * 64;
    const int tid = threadIdx.x;

    // ---- load + pack: task t = tid + 256*i ; c2 = t>>4 (0..63), g = t&15 ----
#pragma unroll
    for (int i = 0; i < 4; ++i) {
        const int t  = tid + 256 * i;
        const int c2 = t >> 4;
        const int g  = t & 15;
        const float4 va = *(const float4*)&x[(size_t)(2 * c2)     * N_NODES + nb + g * 4];
        const float4 vb = *(const float4*)&x[(size_t)(2 * c2 + 1) * N_NODES + nb + g * 4];
        lds[(g * 4 + 0) * 65 + c2] = pack_bf16x2(va.x, vb.x);
        lds[(g * 4 + 1) * 65 + c2] = pack_bf16x2(va.y, vb.y);
        lds[(g * 4 + 2) * 65 + c2] = pack_bf16x2(va.z, vb.z);
        lds[(g * 4 + 3) * 65 + c2] = pack_bf16x2(va.w, vb.w);
    }
    __syncthreads();

    // ---- write: thread (n = tid>>2, q = tid&3) -> 64 B contiguous;
    //      wave -> 16 complete rows = 4 KB contiguous ----
    const int n = tid >> 2, q = tid & 3;
    const unsigned* src = &lds[n * 65 + q * 16];
    unsigned* dst = &xTb[(size_t)(nb + n) * 64 + q * 16];
#pragma unroll
    for (int jj = 0; jj < 4; ++jj) {
        uint4 v = make_uint4(src[4 * jj + 0], src[4 * jj + 1],
                             src[4 * jj + 2], src[4 * jj + 3]);
        *(uint4*)&dst[4 * jj] = v;
    }
}

// ---------------------------------------------------------------------------
// Kernel 2: fused gather-sum + MFMA GEMM (folded W') + relu/bias epilogue.
// Block = 256 threads (4 waves), 32 nodes/block, grid = 1250.
// ---------------------------------------------------------------------------
__global__ __launch_bounds__(256) void fused3_kernel(
        const unsigned* __restrict__ xTb,     // [N][64] u32 = bf16x2
        const float*    __restrict__ x0,      // [N][128] f32
        const int*      __restrict__ e0,      // [N][16]
        const bf16x8*   __restrict__ WB,      // 64 frags x 64 lanes x 16B
        const float*    __restrict__ bias,    // [128]
        float*          __restrict__ out) {   // [128][N]
    __shared__ unsigned y[32][132];           // [node][sum(64) | x0(64) | pad 4]
    __shared__ int eis[512];

    const int nb   = blockIdx.x * 32;
    const int tid  = threadIdx.x;
    const int lane = tid & 63;
    const int wid  = tid >> 6;

    eis[tid]       = e0[(size_t)nb * K_NBR + tid];
    eis[256 + tid] = e0[(size_t)nb * K_NBR + 256 + tid];
    __syncthreads();

    // ---- Phase 1: paired gather (half-wave per node, 4 channels/lane) ----
    const int h  = lane >> 5;
    const int l5 = lane & 31;
#pragma unroll 2
    for (int p4 = 0; p4 < 4; ++p4) {
        const int local = wid * 8 + p4 * 2 + h;
        const int n = nb + local;
        const uint2 sv = *(const uint2*)&xTb[(size_t)n * 64 + 2 * l5];
        float a0 = bflo(sv.x), a1 = bfhi(sv.x);
        float a2 = bflo(sv.y), a3 = bfhi(sv.y);
        const int* ep = &eis[local * K_NBR];
#pragma unroll
        for (int k = 0; k < K_NBR; ++k) {
            const int j = ep[k];
            const uint2 v = *(const uint2*)&xTb[(size_t)j * 64 + 2 * l5];
            a0 += bflo(v.x); a1 += bfhi(v.x);
            a2 += bflo(v.y); a3 += bfhi(v.y);
        }
        *(uint2*)&y[local][2 * l5] =
            make_uint2(pack_bf16x2(a0, a1), pack_bf16x2(a2, a3));
        const float4 xv = *(const float4*)&x0[(size_t)n * C_DIM + 4 * l5];
        *(uint2*)&y[local][64 + 2 * l5] =
            make_uint2(pack_bf16x2(xv.x, xv.y), pack_bf16x2(xv.z, xv.w));
    }
    __syncthreads();

    // ---- Phase 2: MFMA GEMM (K=256) ----
    const int nh = wid & 1;
    const int oh = wid >> 1;
    const int arow = nh * 16 + (lane & 15);
    const int acol = (lane >> 4) * 4;

    bf16x8 afrag[8];
#pragma unroll
    for (int kb = 0; kb < 8; ++kb)
        afrag[kb] = *(const bf16x8*)&y[arow][kb * 16 + acol];

    f32x4 acc[4];
#pragma unroll
    for (int t = 0; t < 4; ++t) {
        f32x4 a = {0.f, 0.f, 0.f, 0.f};
#pragma unroll
        for (int kb = 0; kb < 8; ++kb) {
            bf16x8 bv = WB[((oh * 4 + t) * 8 + kb) * 64 + lane];
            a = __builtin_amdgcn_mfma_f32_16x16x32_bf16(afrag[kb], bv, a, 0, 0, 0);
        }
        acc[t] = a;
    }

    // ---- Phase 3: relu(acc + bias), store [C][N] ----
    const int rbase = nh * 16 + (lane >> 4) * 4;
#pragma unroll
    for (int t = 0; t < 4; ++t) {
        const int o = oh * 64 + t * 16 + (lane & 15);
        const float bo = bias[o];
        float4 res;
        res.x = fmaxf(acc[t][0] + bo, 0.0f);
        res.y = fmaxf(acc[t][1] + bo, 0.0f);
        res.z = fmaxf(acc[t][2] + bo, 0.0f);
        res.w = fmaxf(acc[t][3] + bo, 0.0f);
        *(float4*)&out[(size_t)o * N_NODES + nb + rbase] = res;
    }
}

// ---------------------------------------------------------------------------
extern "C" void kernel_launch(void* const* d_in, const int* in_sizes, int n_in,
                              void* d_out, int out_size, void* d_ws, size_t ws_size,
                              hipStream_t stream) {
    const float* x    = (const float*)d_in[0];   // [1,128,40000,1]
    const float* x0   = (const float*)d_in[1];   // [1,40000,128]
    const int*   ei   = (const int*)  d_in[2];   // [2,1,40000,16]; row 0
    const float* W1   = (const float*)d_in[3];   // [128,128]
    const float* W2   = (const float*)d_in[4];   // [128,128]
    const float* bias = (const float*)d_in[5];   // [128]
    float* out = (float*)d_out;                  // [1,128,40000,1]

    // ws: [0, 64KB) WB' bf16 frags ; [64KB, 64KB+10.24MB) xTb
    unsigned short* WB  = (unsigned short*)d_ws;
    unsigned*       xTb = (unsigned*)((char*)d_ws + 65536);

    hipLaunchKernelGGL(prep_kernel, dim3(753), dim3(256), 0, stream,
                       x, W1, W2, xTb, WB);
    hipLaunchKernelGGL(fused3_kernel, dim3(1250), dim3(256), 0, stream,
                       xTb, x0, ei, (const bf16x8*)WB, bias, out);
}

// Round 7
// 40.865 us; speedup vs baseline: 1.6552x; 1.0507x over previous
//
#include <hip/hip_runtime.h>

#define N_NODES 40000
#define C_DIM   128
#define K_NBR   16

static constexpr float BETA_F  = 0.11778303565638346f;  // log(1.125)
static constexpr float C1_F    = 0.7939952679092549f;   // (1-ALPHA)*(1-BETA)
static constexpr float C2_F    = 0.08822169643436166f;  // ALPHA*(1-BETA)
static constexpr float INV_DEG = 1.0f / 17.0f;

typedef __attribute__((ext_vector_type(8))) short bf16x8;
typedef __attribute__((ext_vector_type(4))) float f32x4;

__device__ __forceinline__ unsigned pack_bf16x2(float a, float b) {
    unsigned ua = __float_as_uint(a), ub = __float_as_uint(b);
    ua += 0x7fffu + ((ua >> 16) & 1u);     // RNE
    ub += 0x7fffu + ((ub >> 16) & 1u);
    return (ua >> 16) | (ub & 0xffff0000u);
}
__device__ __forceinline__ float bflo(unsigned u) { return __uint_as_float(u << 16); }
__device__ __forceinline__ float bfhi(unsigned u) { return __uint_as_float(u & 0xffff0000u); }

// ---------------------------------------------------------------------------
// Kernel 1 (prep), grid = 128 + 1250 blocks:
//   blocks 0..127    : folded-W fragment build (parallel, 1 elem/thread).
//   blocks 128..1377 : transpose+cast 32 nodes x 128 channels of
//                      x [128][40000] f32 -> xTb [N][64] u32(bf16x2).
//                      1250 blocks (~5.4/CU, ~21 waves/CU) + 4 independent
//                      float4 loads per thread -> HBM-bound, not
//                      latency-bound (R6's 625-block version ran ~1.5 TB/s).
// W'[c][o] = c<128 ? (BETA*W1[o][c] + (c==o)*C1) * INV_DEG
//                  : BETA*W2[o][c-128] + (c-128==o)*C2
// Fragment map = A-frag slot map: frag f = otile*8+kblk;
// o = otile*16+(lane&15), c = kblk*32+(lane>>4)*8+j.
// ---------------------------------------------------------------------------
__global__ __launch_bounds__(256) void prep_kernel(
        const float* __restrict__ x,
        const float* __restrict__ W1,
        const float* __restrict__ W2,
        unsigned* __restrict__ xTb,
        unsigned short* __restrict__ WB) {
    __shared__ unsigned lds[32 * 65];   // [n][c2], stride 65 u32 (8320 B)

    const int b = blockIdx.x;
    const int tid = threadIdx.x;

    if (b < 128) {
        const int i = b * 256 + tid;                   // 0 .. 32767
        const int frag = i >> 9, within = i & 511;
        const int lane = within >> 3, j = within & 7;
        const int otile = frag >> 3, kblk = frag & 7;
        const int o = otile * 16 + (lane & 15);
        const int c = kblk * 32 + ((lane >> 4) << 3) + j;
        float v;
        if (c < 128) {
            v = (BETA_F * W1[o * 128 + c] + (c == o ? C1_F : 0.0f)) * INV_DEG;
        } else {
            const int c2 = c - 128;
            v = BETA_F * W2[o * 128 + c2] + (c2 == o ? C2_F : 0.0f);
        }
        unsigned u = __float_as_uint(v);
        u += 0x7fffu + ((u >> 16) & 1u);
        WB[i] = (unsigned short)(u >> 16);
        return;
    }

    const int nb = (b - 128) * 32;

    // ---- load: thread (c2 = tid>>2, h = tid&3) reads 8 n of rows 2c2,2c2+1
    //      as 4 INDEPENDENT float4 loads (issued together -> ILP) ----
    const int c2 = tid >> 2;          // 0..63
    const int h  = tid & 3;           // n-offset h*8
    const float* r0 = &x[(size_t)(2 * c2)     * N_NODES + nb + h * 8];
    const float* r1 = &x[(size_t)(2 * c2 + 1) * N_NODES + nb + h * 8];
    const float4 a0 = *(const float4*)(r0);
    const float4 a1 = *(const float4*)(r0 + 4);
    const float4 b0 = *(const float4*)(r1);
    const float4 b1 = *(const float4*)(r1 + 4);

    unsigned* lrow = &lds[h * 8 * 65 + c2];
    lrow[0 * 65] = pack_bf16x2(a0.x, b0.x);
    lrow[1 * 65] = pack_bf16x2(a0.y, b0.y);
    lrow[2 * 65] = pack_bf16x2(a0.z, b0.z);
    lrow[3 * 65] = pack_bf16x2(a0.w, b0.w);
    lrow[4 * 65] = pack_bf16x2(a1.x, b1.x);
    lrow[5 * 65] = pack_bf16x2(a1.y, b1.y);
    lrow[6 * 65] = pack_bf16x2(a1.z, b1.z);
    lrow[7 * 65] = pack_bf16x2(a1.w, b1.w);
    __syncthreads();

    // ---- write: thread (n = tid>>3, q = tid&7) -> 32 B contiguous;
    //      wave -> 8 complete 256-B rows = 2 KB contiguous ----
    const int n = tid >> 3, q = tid & 7;
    const unsigned* src = &lds[n * 65 + q * 8];
    unsigned* dst = &xTb[(size_t)(nb + n) * 64 + q * 8];
    *(uint4*)&dst[0] = make_uint4(src[0], src[1], src[2], src[3]);
    *(uint4*)&dst[4] = make_uint4(src[4], src[5], src[6], src[7]);
}

// ---------------------------------------------------------------------------
// Kernel 2: fused gather-sum + MFMA GEMM (folded W') + relu/bias epilogue.
// Block = 256 threads (4 waves), 32 nodes/block, grid = 1250.
// ---------------------------------------------------------------------------
__global__ __launch_bounds__(256) void fused3_kernel(
        const unsigned* __restrict__ xTb,     // [N][64] u32 = bf16x2
        const float*    __restrict__ x0,      // [N][128] f32
        const int*      __restrict__ e0,      // [N][16]
        const bf16x8*   __restrict__ WB,      // 64 frags x 64 lanes x 16B
        const float*    __restrict__ bias,    // [128]
        float*          __restrict__ out) {   // [128][N]
    __shared__ unsigned y[32][132];           // [node][sum(64) | x0(64) | pad 4]
    __shared__ int eis[512];

    const int nb   = blockIdx.x * 32;
    const int tid  = threadIdx.x;
    const int lane = tid & 63;
    const int wid  = tid >> 6;

    eis[tid]       = e0[(size_t)nb * K_NBR + tid];
    eis[256 + tid] = e0[(size_t)nb * K_NBR + 256 + tid];
    __syncthreads();

    // ---- Phase 1: paired gather (half-wave per node, 4 channels/lane) ----
    const int h  = lane >> 5;
    const int l5 = lane & 31;
#pragma unroll 2
    for (int p4 = 0; p4 < 4; ++p4) {
        const int local = wid * 8 + p4 * 2 + h;
        const int n = nb + local;
        const uint2 sv = *(const uint2*)&xTb[(size_t)n * 64 + 2 * l5];
        float a0 = bflo(sv.x), a1 = bfhi(sv.x);
        float a2 = bflo(sv.y), a3 = bfhi(sv.y);
        const int* ep = &eis[local * K_NBR];
#pragma unroll
        for (int k = 0; k < K_NBR; ++k) {
            const int j = ep[k];
            const uint2 v = *(const uint2*)&xTb[(size_t)j * 64 + 2 * l5];
            a0 += bflo(v.x); a1 += bfhi(v.x);
            a2 += bflo(v.y); a3 += bfhi(v.y);
        }
        *(uint2*)&y[local][2 * l5] =
            make_uint2(pack_bf16x2(a0, a1), pack_bf16x2(a2, a3));
        const float4 xv = *(const float4*)&x0[(size_t)n * C_DIM + 4 * l5];
        *(uint2*)&y[local][64 + 2 * l5] =
            make_uint2(pack_bf16x2(xv.x, xv.y), pack_bf16x2(xv.z, xv.w));
    }
    __syncthreads();

    // ---- Phase 2: MFMA GEMM (K=256) ----
    const int nh = wid & 1;
    const int oh = wid >> 1;
    const int arow = nh * 16 + (lane & 15);
    const int acol = (lane >> 4) * 4;

    bf16x8 afrag[8];
#pragma unroll
    for (int kb = 0; kb < 8; ++kb)
        afrag[kb] = *(const bf16x8*)&y[arow][kb * 16 + acol];

    f32x4 acc[4];
#pragma unroll
    for (int t = 0; t < 4; ++t) {
        f32x4 a = {0.f, 0.f, 0.f, 0.f};
#pragma unroll
        for (int kb = 0; kb < 8; ++kb) {
            bf16x8 bv = WB[((oh * 4 + t) * 8 + kb) * 64 + lane];
            a = __builtin_amdgcn_mfma_f32_16x16x32_bf16(afrag[kb], bv, a, 0, 0, 0);
        }
        acc[t] = a;
    }

    // ---- Phase 3: relu(acc + bias), store [C][N] ----
    const int rbase = nh * 16 + (lane >> 4) * 4;
#pragma unroll
    for (int t = 0; t < 4; ++t) {
        const int o = oh * 64 + t * 16 + (lane & 15);
        const float bo = bias[o];
        float4 res;
        res.x = fmaxf(acc[t][0] + bo, 0.0f);
        res.y = fmaxf(acc[t][1] + bo, 0.0f);
        res.z = fmaxf(acc[t][2] + bo, 0.0f);
        res.w = fmaxf(acc[t][3] + bo, 0.0f);
        *(float4*)&out[(size_t)o * N_NODES + nb + rbase] = res;
    }
}

// ---------------------------------------------------------------------------
extern "C" void kernel_launch(void* const* d_in, const int* in_sizes, int n_in,
                              void* d_out, int out_size, void* d_ws, size_t ws_size,
                              hipStream_t stream) {
    const float* x    = (const float*)d_in[0];   // [1,128,40000,1]
    const float* x0   = (const float*)d_in[1];   // [1,40000,128]
    const int*   ei   = (const int*)  d_in[2];   // [2,1,40000,16]; row 0
    const float* W1   = (const float*)d_in[3];   // [128,128]
    const float* W2   = (const float*)d_in[4];   // [128,128]
    const float* bias = (const float*)d_in[5];   // [128]
    float* out = (float*)d_out;                  // [1,128,40000,1]

    // ws: [0, 64KB) WB' bf16 frags ; [64KB, 64KB+10.24MB) xTb
    unsigned short* WB  = (unsigned short*)d_ws;
    unsigned*       xTb = (unsigned*)((char*)d_ws + 65536);

    hipLaunchKernelGGL(prep_kernel, dim3(1378), dim3(256), 0, stream,
                       x, W1, W2, xTb, WB);
    hipLaunchKernelGGL(fused3_kernel, dim3(1250), dim3(256), 0, stream,
                       xTb, x0, ei, (const bf16x8*)WB, bias, out);
}